// Round 18
// baseline (417.650 us; speedup 1.0000x reference)
//
#include <hip/hip_runtime.h>
#include <cfloat>

#define NB 4
#define NN 4096
#define NS 1024
#define NC1 128
#define NC2 256
#define NCO 128
#define NCC 384
#define NK 16
#define KCHUNK 2048
#define KCAP 160
#define KPAD 161

// NOTE on numerics: the reference computes squared distances in the EXPANDED
// form ||a||^2 + ||b||^2 - 2 a.b (see _sqdist). Top-k selections sit on
// near-ties whose resolution depends on the exact fp bits, so both selection
// kernels below replicate numpy's op order exactly with non-contractible
// __fmul_rn/__fadd_rn/__fsub_rn (no FMA fusion allowed).
//
// PERF CALIBRATION (measured R5/R11/R13-R17): the knn fallback path
// (per-group uncoalesced global rescan) costs ~100+ us per trigger and
// stalls its whole block via the final barrier -> temporal occupancy
// collapse. tau MUST be tight enough that P(survivors > KCAP) ~ 0:
// R16/R17's loose chunk0-tau (~4e-3/query) regressed 2-3x. Pair-combined
// tau (rank ~ max-of-4 Gamma(2,8)) gives P ~ 1.7e-7/query.

__device__ __forceinline__ float norm3_np(float x, float y, float z) {
  return __fadd_rn(__fadd_rn(__fmul_rn(x, x), __fmul_rn(y, y)), __fmul_rn(z, z));
}

__device__ __forceinline__ float sqdist_np(float nq, float ns,
                                           float qx, float qy, float qz,
                                           float sx, float sy, float sz) {
  float dot = __fadd_rn(__fadd_rn(__fmul_rn(qx, sx), __fmul_rn(qy, sy)),
                        __fmul_rn(qz, sz));
  return __fsub_rn(__fadd_rn(nq, ns), __fmul_rn(2.0f, dot));
}

// ---------- generic 32x32 LDS-tiled transpose with strided output ----------
__global__ void transpose_k(const float* __restrict__ in, float* __restrict__ out,
                            int rows_in, int cols_in, long in_bs, long out_bs, int out_rs) {
  __shared__ float tile[32][33];
  const int b = blockIdx.z;
  const int c0 = blockIdx.x * 32, r0 = blockIdx.y * 32;
  const float* ib = in + (long)b * in_bs;
  float* ob = out + (long)b * out_bs;
#pragma unroll
  for (int k = 0; k < 32; k += 8) {
    tile[threadIdx.y + k][threadIdx.x] =
        ib[(long)(r0 + threadIdx.y + k) * cols_in + c0 + threadIdx.x];
  }
  __syncthreads();
#pragma unroll
  for (int k = 0; k < 32; k += 8) {
    ob[(long)(c0 + threadIdx.y + k) * out_rs + (r0 + threadIdx.x)] =
        tile[threadIdx.x][threadIdx.y + k];
  }
}

// ---------- 3-point interpolation: top-3 LARGEST distances (faithful) ----------
// block: 256 threads = 32 queries x 8 lanes; grid (N/32, B)
__global__ __launch_bounds__(256) void interp_top3_k(const float* __restrict__ xyz1,
                                                     const float* __restrict__ xyz2,
                                                     float* __restrict__ wW,
                                                     int* __restrict__ wIdx) {
  __shared__ float sx[NS], sy[NS], sz[NS], sn[NS];
  __shared__ float md[256 * 3];
  __shared__ int mi[256 * 3];
  const int b = blockIdx.y;
  const int tid = threadIdx.x;
  for (int i = tid; i < NS; i += 256) {
    long base = ((long)b * NS + i) * 3;
    float x = xyz2[base], y = xyz2[base + 1], z = xyz2[base + 2];
    sx[i] = x; sy[i] = y; sz[i] = z;
    sn[i] = norm3_np(x, y, z);
  }
  __syncthreads();
  const int q = (blockIdx.x << 5) + (tid >> 3);
  const int lane = tid & 7;
  long qb = ((long)b * NN + q) * 3;
  const float qx = xyz1[qb], qy = xyz1[qb + 1], qz = xyz1[qb + 2];
  const float nq = norm3_np(qx, qy, qz);
  float bd[3] = {-FLT_MAX, -FLT_MAX, -FLT_MAX};
  int bi[3] = {0x7fffffff, 0x7fffffff, 0x7fffffff};
  for (int s = lane; s < NS; s += 8) {
    float d = sqdist_np(nq, sn[s], qx, qy, qz, sx[s], sy[s], sz[s]);
    if (d > bd[2]) {   // guard: ladder is a no-op when d <= bd[2]
      float cd = d; int ci = s;
#pragma unroll
      for (int j = 0; j < 3; ++j) {
        bool gt = cd > bd[j];                // strict: tie keeps earlier (lower idx)
        float f = fmaxf(cd, bd[j]);
        float bk = fminf(cd, bd[j]);
        int fi = gt ? ci : bi[j];
        int ki = gt ? bi[j] : ci;
        bd[j] = f; bi[j] = fi; cd = bk; ci = ki;
      }
    }
  }
#pragma unroll
  for (int j = 0; j < 3; ++j) { md[tid * 3 + j] = bd[j]; mi[tid * 3 + j] = bi[j]; }
  __syncthreads();
  if (lane == 0) {
    int p0 = 0, p1 = 0, p2 = 0, p3 = 0, p4 = 0, p5 = 0, p6 = 0, p7 = 0;
    float od[3]; int oi[3];
#pragma unroll
    for (int j = 0; j < 3; ++j) {
      float bv = -FLT_MAX; int bidx = 0x7fffffff; int bl = 0;
#define ITOP_CAND(l, pl)                                                     \
      {                                                                      \
        float t = (pl < 3) ? md[(tid + l) * 3 + pl] : -FLT_MAX;              \
        int ti = (pl < 3) ? mi[(tid + l) * 3 + pl] : 0x7fffffff;             \
        if (t > bv || (t == bv && ti < bidx)) { bv = t; bidx = ti; bl = l; } \
      }
      ITOP_CAND(0, p0) ITOP_CAND(1, p1) ITOP_CAND(2, p2) ITOP_CAND(3, p3)
      ITOP_CAND(4, p4) ITOP_CAND(5, p5) ITOP_CAND(6, p6) ITOP_CAND(7, p7)
#undef ITOP_CAND
      od[j] = bv; oi[j] = bidx;
      p0 += (bl == 0); p1 += (bl == 1); p2 += (bl == 2); p3 += (bl == 3);
      p4 += (bl == 4); p5 += (bl == 5); p6 += (bl == 6); p7 += (bl == 7);
    }
    float r0 = 1.f / (od[0] + 1e-8f);
    float r1 = 1.f / (od[1] + 1e-8f);
    float r2 = 1.f / (od[2] + 1e-8f);
    float sR = __fadd_rn(__fadd_rn(r0, r1), r2);
    long obase = ((long)b * NN + q) * 3;
    wW[obase + 0] = r0 / sR; wW[obase + 1] = r1 / sR; wW[obase + 2] = r2 / sR;
    wIdx[obase + 0] = oi[0]; wIdx[obase + 1] = oi[1]; wIdx[obase + 2] = oi[2];
  }
}

// ---------- fill interp channels of nt (cols 128..383) ----------
__global__ __launch_bounds__(256) void interp_fill_k(const float* __restrict__ p2t,
                                                     const float* __restrict__ wW,
                                                     const int* __restrict__ wIdx,
                                                     float* __restrict__ nt) {
  const int q = (blockIdx.x << 1) + (threadIdx.x >> 7);
  const int co = threadIdx.x & 127;
  const int b = q >> 12;
  long wb = (long)q * 3;
  float w0 = wW[wb], w1 = wW[wb + 1], w2 = wW[wb + 2];
  int i0 = wIdx[wb], i1 = wIdx[wb + 1], i2 = wIdx[wb + 2];
  const float* r0 = p2t + ((long)(b << 10) + i0) * NC2;
  const float* r1 = p2t + ((long)(b << 10) + i1) * NC2;
  const float* r2 = p2t + ((long)(b << 10) + i2) * NC2;
  float* orow = nt + (long)q * NCC + NC1;
#pragma unroll
  for (int h = 0; h < 2; ++h) {
    int c = co + 128 * h;
    orow[c] = w0 * r0[c] + w1 * r1[c] + w2 * r2[c];
  }
}

// ---------- f32 tiled GEMM: 64 rows x 64 output channels per block ----------
template <int C>
__global__ __launch_bounds__(256) void gemm_bias_k(const float* __restrict__ feat,
                                                   const float* __restrict__ W,
                                                   const float* __restrict__ bias,
                                                   float* __restrict__ out) {
  __shared__ float fL[64][36];
  __shared__ float wL[64][36];
  const int r0 = blockIdx.x * 64;
  const int ob = blockIdx.y * 64;
  const int tid = threadIdx.x;
  const int tn = tid & 15;
  const int to = tid >> 4;
  float acc[4][4];
#pragma unroll
  for (int i = 0; i < 4; ++i)
#pragma unroll
    for (int j = 0; j < 4; ++j) acc[i][j] = 0.f;

  for (int c0 = 0; c0 < C; c0 += 32) {
#pragma unroll
    for (int k = 0; k < 8; ++k) {
      int e = tid + 256 * k;
      int rr = e >> 5, cc = e & 31;
      fL[rr][cc] = feat[(long)(r0 + rr) * C + c0 + cc];
    }
#pragma unroll
    for (int k = 0; k < 8; ++k) {
      int e = tid + 256 * k;
      int rr = e >> 5, cc = e & 31;
      wL[rr][cc] = W[(long)(ob + rr) * C + c0 + cc];
    }
    __syncthreads();
#pragma unroll
    for (int cc4 = 0; cc4 < 32; cc4 += 4) {
      float4 fv[4], wv[4];
#pragma unroll
      for (int i = 0; i < 4; ++i) fv[i] = *(const float4*)&fL[tn + 16 * i][cc4];
#pragma unroll
      for (int j = 0; j < 4; ++j) wv[j] = *(const float4*)&wL[to + 16 * j][cc4];
#pragma unroll
      for (int i = 0; i < 4; ++i)
#pragma unroll
        for (int j = 0; j < 4; ++j) {
          acc[i][j] += fv[i].x * wv[j].x + fv[i].y * wv[j].y +
                       fv[i].z * wv[j].z + fv[i].w * wv[j].w;
        }
    }
    __syncthreads();
  }
  const int b = r0 >> 12;
  const int n0 = r0 & 4095;
#pragma unroll
  for (int i = 0; i < 4; ++i) {
    int n = n0 + tn + 16 * i;
#pragma unroll
    for (int j = 0; j < 4; ++j) {
      int o = ob + to + 16 * j;
      out[((long)(b * NCO + o) << 12) + n] = acc[i][j] + bias[o];
    }
  }
}

// ---------- BN stats per channel over (B, N): single pass (sum, sumsq) ----------
__global__ __launch_bounds__(256) void bn_stats_k(const float* __restrict__ v,
                                                  const float* __restrict__ gamma,
                                                  const float* __restrict__ beta,
                                                  float* __restrict__ stats, int relu_in) {
  __shared__ float rs[256], rq[256];
  const int o = blockIdx.x, tid = threadIdx.x;
  float s = 0.f, ss = 0.f;
  for (int i = tid; i < NB * NN; i += 256) {
    int b = i >> 12, n = i & 4095;
    float val = v[(((long)b * NCO + o) << 12) + n];
    if (relu_in) val = fmaxf(val, 0.f);
    s += val;
    ss += val * val;
  }
  rs[tid] = s; rq[tid] = ss;
  __syncthreads();
  for (int off = 128; off > 0; off >>= 1) {
    if (tid < off) { rs[tid] += rs[tid + off]; rq[tid] += rq[tid + off]; }
    __syncthreads();
  }
  if (tid == 0) {
    float m = rs[0] * (1.f / 16384.f);
    float var = rq[0] * (1.f / 16384.f) - m * m;
    var = fmaxf(var, 0.f);
    float inv = rsqrtf(var + 1e-5f);
    stats[o] = m;
    stats[128 + o] = inv * gamma[o];
    stats[256 + o] = beta[o];
  }
}

// ---------- apply fuse BN + ReLU (tiled): write x [B,CO,N] + xt [B,N,CO] ----------
// grid (N/32, CO/32, B), block (32,8).
__global__ void fuse_apply_k(const float* __restrict__ xp, const float* __restrict__ stats,
                             float* __restrict__ x, float* __restrict__ xt) {
  __shared__ float tile[32][33];
  const int b = blockIdx.z;
  const int n0 = blockIdx.x * 32;
  const int o0 = blockIdx.y * 32;
  const int tx = threadIdx.x, ty = threadIdx.y;
#pragma unroll
  for (int k = 0; k < 32; k += 8) {
    int o = o0 + ty + k;
    long idx = (((long)b * NCO + o) << 12) + n0 + tx;
    float v = (xp[idx] - stats[o]) * stats[128 + o] + stats[256 + o];
    v = fmaxf(v, 0.f);
    x[idx] = v;
    tile[ty + k][tx] = v;
  }
  __syncthreads();
#pragma unroll
  for (int k = 0; k < 32; k += 8) {
    int n = n0 + ty + k;
    xt[((long)(b << 12) + n) * NCO + o0 + tx] = tile[tx][ty + k];
  }
}

// ---------- KNN(16): single-restage + PAIR-COMBINED tight tau; 32 q x 8 lanes ----------
// Structure: stage chunk0 -> pass1 over chunk0 -> tau -> pass2 over chunk0
// (no re-stage) -> barrier -> stage chunk1 -> pass2 over chunk1.
// tau: per-lane top-2 (4 trackers) -> PAIR-combine via shfl_xor(1) (exact
//   2nd-smallest of the pair's 512-candidate chunk0 stream; R6-proven
//   min(max(a0,b0),min(a1,b1))) -> max over the query's 4 pairs.
//   >=16 candidates (2 per pair x ... actually 2 per pair, 4 pairs = 8; plus
//   pair-2nd bound guarantees 2 per pair <= pair-tau; the max over pairs
//   makes all 4 pairs' top-2 (8 candidates) <= tau -- and each pair's top-2
//   are 2 of 512 DISTINCT candidates; tau >= each pair's 2nd-smallest, so
//   each pair contributes >=2 survivors => >=8? Correction: safety needs 16.
//   Stronger argument: tau >= pair p's 2nd-smallest for ALL p, and also
//   tau >= per-lane 2nd-smallest for both lanes of the max pair... Simplest
//   sufficient check: tau here >= the OLD per-lane-max tau? No -- it is
//   TIGHTER. Safety from first principles: survivors(tau) >= sum over pairs
//   of #{pair candidates <= tau} >= sum over pairs of 2 = 8... 
//   => NOT sufficient for 16 alone. HOWEVER pass 3 selects top-16 from
//   survivors; if survivors < 16 the result would be wrong. Fix: use
//   pair 4th-smallest instead: union of two lanes' top-2s = 4 values, all
//   >= 4 distinct candidates; tau = max over pairs of pair-4th => each pair
//   contributes >=4 survivors => >=16 total. pair-4th = max(a1, b1).
//   (rank of max(a1,b1) in 512-stream: max of two Gamma(2,16)-ish ranks
//   ~ mean 26; max over 4 pairs ~ 45 survivors; P(>160) ~ 1e-5/query.)
// Fallback (P ~ 1e-5/query, ~0.2 triggers/run): tau-guarded global rescan
//   (correct, slow -- kept off the critical path by the tight tau).
__global__ __launch_bounds__(256) void knn_k(const float* __restrict__ xyz1,
                                             int* __restrict__ knn) {
  __shared__ float4 sc[KCHUNK];      // 32 KB; reused as merge lists at the end
  __shared__ float bufd[32][KPAD];   // 20.1 KB
  __shared__ int bufi[32][KPAD];     // 20.1 KB
  const int b = blockIdx.y;
  const int tid = threadIdx.x;
  const int ql = tid >> 3;
  const int q = (blockIdx.x << 5) + ql;
  const int lane = tid & 7;
  const int gb = (tid & 63) - lane;  // group base lane within the wave
  const long qb = ((long)b * NN + q) * 3;
  const float qx = xyz1[qb], qy = xyz1[qb + 1], qz = xyz1[qb + 2];
  const float nq = norm3_np(qx, qy, qz);

  // ---- stage chunk 0 ----
  for (int i = tid; i < KCHUNK; i += 256) {
    long base = ((long)b * NN + i) * 3;
    float x = xyz1[base], y = xyz1[base + 1], z = xyz1[base + 2];
    sc[i] = make_float4(x, y, z, norm3_np(x, y, z));
  }
  __syncthreads();

  // ---- pass 1 over chunk 0: per-lane top-2 via 4 independent trackers ----
  float ta0 = FLT_MAX, ta1 = FLT_MAX, tb0 = FLT_MAX, tb1 = FLT_MAX;
  float tc0 = FLT_MAX, tc1 = FLT_MAX, td0 = FLT_MAX, td1 = FLT_MAX;
  for (int i = lane; i < KCHUNK; i += 32) {
    float4 v0 = sc[i], v1 = sc[i + 8], v2 = sc[i + 16], v3 = sc[i + 24];
    float d0 = sqdist_np(nq, v0.w, qx, qy, qz, v0.x, v0.y, v0.z);
    float d1 = sqdist_np(nq, v1.w, qx, qy, qz, v1.x, v1.y, v1.z);
    float d2 = sqdist_np(nq, v2.w, qx, qy, qz, v2.x, v2.y, v2.z);
    float d3 = sqdist_np(nq, v3.w, qx, qy, qz, v3.x, v3.y, v3.z);
    float h0 = fmaxf(d0, ta0); ta0 = fminf(d0, ta0); ta1 = fminf(h0, ta1);
    float h1 = fmaxf(d1, tb0); tb0 = fminf(d1, tb0); tb1 = fminf(h1, tb1);
    float h2 = fmaxf(d2, tc0); tc0 = fminf(d2, tc0); tc1 = fminf(h2, tc1);
    float h3 = fmaxf(d3, td0); td0 = fminf(d3, td0); td1 = fminf(h3, td1);
  }
  // per-lane 2nd-smallest (of the lane's 256-cand stream; ties -> looser, safe)
  float m1 = fminf(fminf(ta0, tb0), fminf(tc0, td0));
  float s0 = (ta0 == m1) ? ta1 : ta0;
  float s1 = (tb0 == m1) ? tb1 : tb0;
  float s2 = (tc0 == m1) ? tc1 : tc0;
  float s3 = (td0 == m1) ? td1 : td0;
  float lane2 = fminf(fminf(s0, s1), fminf(s2, s3));
  // pair 4th-smallest bound: max of the two lanes' 2nd-smallests. Each pair
  // (512 distinct candidates) then has >=4 candidates <= it; max over the
  // query's 4 pairs => >=16 candidates <= tau => d16 <= tau: SAFE.
  float pair4 = fmaxf(lane2, __shfl_xor(lane2, 1, 64));
  float tau = pair4;
  tau = fmaxf(tau, __shfl_xor(tau, 2, 64));
  tau = fmaxf(tau, __shfl_xor(tau, 4, 64));

  // ---- pass 2 over chunk 0 (sc still staged -- no re-stage) ----
  int mycnt = 0;  // survivor count for this query; uniform across its 8 lanes
  unsigned below = (1u << lane) - 1u;
  for (int i = lane; i < KCHUNK; i += 32) {
    float4 v0 = sc[i], v1 = sc[i + 8], v2 = sc[i + 16], v3 = sc[i + 24];
    float d0 = sqdist_np(nq, v0.w, qx, qy, qz, v0.x, v0.y, v0.z);
    float d1 = sqdist_np(nq, v1.w, qx, qy, qz, v1.x, v1.y, v1.z);
    float d2 = sqdist_np(nq, v2.w, qx, qy, qz, v2.x, v2.y, v2.z);
    float d3 = sqdist_np(nq, v3.w, qx, qy, qz, v3.x, v3.y, v3.z);
    bool sv0 = (d0 <= tau), sv1 = (d1 <= tau), sv2 = (d2 <= tau), sv3 = (d3 <= tau);
    unsigned long long m0 = __ballot(sv0);
    unsigned long long m1b = __ballot(sv1);
    unsigned long long m2 = __ballot(sv2);
    unsigned long long m3 = __ballot(sv3);
    unsigned g0 = (unsigned)((m0 >> gb) & 0xFFull);
    unsigned g1 = (unsigned)((m1b >> gb) & 0xFFull);
    unsigned g2 = (unsigned)((m2 >> gb) & 0xFFull);
    unsigned g3 = (unsigned)((m3 >> gb) & 0xFFull);
    int c0p = __popc(g0), c1p = __popc(g1), c2p = __popc(g2);
    if (sv0) {
      int pos = mycnt + __popc(g0 & below);
      if (pos < KCAP) { bufd[ql][pos] = d0; bufi[ql][pos] = i; }
    }
    if (sv1) {
      int pos = mycnt + c0p + __popc(g1 & below);
      if (pos < KCAP) { bufd[ql][pos] = d1; bufi[ql][pos] = i + 8; }
    }
    if (sv2) {
      int pos = mycnt + c0p + c1p + __popc(g2 & below);
      if (pos < KCAP) { bufd[ql][pos] = d2; bufi[ql][pos] = i + 16; }
    }
    if (sv3) {
      int pos = mycnt + c0p + c1p + c2p + __popc(g3 & below);
      if (pos < KCAP) { bufd[ql][pos] = d3; bufi[ql][pos] = i + 24; }
    }
    mycnt += c0p + c1p + c2p + __popc(g3);
  }
  __syncthreads();

  // ---- stage chunk 1 + pass 2 over it ----
  for (int i = tid; i < KCHUNK; i += 256) {
    long base = ((long)b * NN + KCHUNK + i) * 3;
    float x = xyz1[base], y = xyz1[base + 1], z = xyz1[base + 2];
    sc[i] = make_float4(x, y, z, norm3_np(x, y, z));
  }
  __syncthreads();
  for (int i = lane; i < KCHUNK; i += 32) {
    float4 v0 = sc[i], v1 = sc[i + 8], v2 = sc[i + 16], v3 = sc[i + 24];
    float d0 = sqdist_np(nq, v0.w, qx, qy, qz, v0.x, v0.y, v0.z);
    float d1 = sqdist_np(nq, v1.w, qx, qy, qz, v1.x, v1.y, v1.z);
    float d2 = sqdist_np(nq, v2.w, qx, qy, qz, v2.x, v2.y, v2.z);
    float d3 = sqdist_np(nq, v3.w, qx, qy, qz, v3.x, v3.y, v3.z);
    bool sv0 = (d0 <= tau), sv1 = (d1 <= tau), sv2 = (d2 <= tau), sv3 = (d3 <= tau);
    unsigned long long m0 = __ballot(sv0);
    unsigned long long m1b = __ballot(sv1);
    unsigned long long m2 = __ballot(sv2);
    unsigned long long m3 = __ballot(sv3);
    unsigned g0 = (unsigned)((m0 >> gb) & 0xFFull);
    unsigned g1 = (unsigned)((m1b >> gb) & 0xFFull);
    unsigned g2 = (unsigned)((m2 >> gb) & 0xFFull);
    unsigned g3 = (unsigned)((m3 >> gb) & 0xFFull);
    int c0p = __popc(g0), c1p = __popc(g1), c2p = __popc(g2);
    if (sv0) {
      int pos = mycnt + __popc(g0 & below);
      if (pos < KCAP) { bufd[ql][pos] = d0; bufi[ql][pos] = KCHUNK + i; }
    }
    if (sv1) {
      int pos = mycnt + c0p + __popc(g1 & below);
      if (pos < KCAP) { bufd[ql][pos] = d1; bufi[ql][pos] = KCHUNK + i + 8; }
    }
    if (sv2) {
      int pos = mycnt + c0p + c1p + __popc(g2 & below);
      if (pos < KCAP) { bufd[ql][pos] = d2; bufi[ql][pos] = KCHUNK + i + 16; }
    }
    if (sv3) {
      int pos = mycnt + c0p + c1p + c2p + __popc(g3 & below);
      if (pos < KCAP) { bufd[ql][pos] = d3; bufi[ql][pos] = KCHUNK + i + 24; }
    }
    mycnt += c0p + c1p + c2p + __popc(g3);
  }
  __syncthreads();

  // ---- pass 3: exact stable top-16 ----
  float bd[NK]; int bi[NK];
#pragma unroll
  for (int j = 0; j < NK; ++j) { bd[j] = FLT_MAX; bi[j] = 0x7fffffff; }
  if (mycnt > KCAP) {
    // fallback: tau-guarded strict-d ladder over global (index order -> stable)
    for (int s = lane; s < NN; s += 8) {
      long base = ((long)b * NN + s) * 3;
      float x = xyz1[base], y = xyz1[base + 1], z = xyz1[base + 2];
      float d = sqdist_np(nq, norm3_np(x, y, z), qx, qy, qz, x, y, z);
      if (d <= tau) {
        float cd = d; int ci = s;
#pragma unroll
        for (int j = 0; j < NK; ++j) {
          bool lt = cd < bd[j];
          float dmin = fminf(cd, bd[j]);
          float dmax = fmaxf(cd, bd[j]);
          int imin = lt ? ci : bi[j];
          int imax = lt ? bi[j] : ci;
          bd[j] = dmin; bi[j] = imin; cd = dmax; ci = imax;
        }
      }
    }
  } else {
    for (int j0 = lane; j0 < mycnt; j0 += 8) {
      float cd = bufd[ql][j0]; int ci = bufi[ql][j0];
#pragma unroll
      for (int j = 0; j < NK; ++j) {
        bool lt = (cd < bd[j]) || (cd == bd[j] && ci < bi[j]);  // lex (d, idx)
        float nd = lt ? cd : bd[j];
        float xd = lt ? bd[j] : cd;
        int ni = lt ? ci : bi[j];
        int xi = lt ? bi[j] : ci;
        bd[j] = nd; bi[j] = ni; cd = xd; ci = xi;
      }
    }
  }
  __syncthreads();  // staging LDS dead; reuse sc for merge lists

  float* md = (float*)sc;        // 256*16 floats = 16 KB
  int* mi = (int*)sc + 4096;     // 256*16 ints  = 16 KB
#pragma unroll
  for (int j = 0; j < NK; ++j) { md[tid * NK + j] = bd[j]; mi[tid * NK + j] = bi[j]; }
  __syncthreads();
  if (lane == 0) {
    int p0 = 0, p1 = 0, p2 = 0, p3 = 0, p4 = 0, p5 = 0, p6 = 0, p7 = 0;
    long obase = ((long)b * NN + q) * NK;
    for (int j = 0; j < NK; ++j) {
      float bv = FLT_MAX; int bidx = 0x7fffffff; int bl = 0;
#define KNN_CAND(l, pl)                                                      \
      {                                                                      \
        float t = (pl < NK) ? md[(tid + l) * NK + pl] : FLT_MAX;             \
        int ti = (pl < NK) ? mi[(tid + l) * NK + pl] : 0x7fffffff;           \
        if (t < bv || (t == bv && ti < bidx)) { bv = t; bidx = ti; bl = l; } \
      }
      KNN_CAND(0, p0) KNN_CAND(1, p1) KNN_CAND(2, p2) KNN_CAND(3, p3)
      KNN_CAND(4, p4) KNN_CAND(5, p5) KNN_CAND(6, p6) KNN_CAND(7, p7)
#undef KNN_CAND
      knn[obase + j] = bidx;
      p0 += (bl == 0); p1 += (bl == 1); p2 += (bl == 2); p3 += (bl == 3);
      p4 += (bl == 4); p5 += (bl == 5); p6 += (bl == 6); p7 += (bl == 7);
    }
  }
}

// ---------- Laplacian gather: dxt[q][o] = sum_k xt[nbr_k][o] - xt[q][o] ----------
__global__ __launch_bounds__(256) void lap_gather_k(const float* __restrict__ xt,
                                                    const int* __restrict__ knn,
                                                    float* __restrict__ dxt) {
  const int q = (blockIdx.x << 1) + (threadIdx.x >> 7);
  const int o = threadIdx.x & 127;
  const int b = q >> 12;
  const int* kid = knn + (long)q * NK;
  const long bb = ((long)b << 12) * NCO;
  float s = 0.f;
#pragma unroll
  for (int k = 0; k < NK; ++k) {
    int m = kid[k];
    s += xt[bb + (long)m * NCO + o];
  }
  dxt[(long)q * NCO + o] = s - xt[(long)q * NCO + o];
}

// ---------- final: out = x + BN(relu(h_pre)) ----------
__global__ void final_k(const float* __restrict__ x, const float* __restrict__ hp,
                        const float* __restrict__ stats, float* __restrict__ out) {
  const int stride = gridDim.x * blockDim.x;
  for (int idx = blockIdx.x * blockDim.x + threadIdx.x; idx < NB * NCO * NN; idx += stride) {
    int o = (idx >> 12) & 127;
    float r = fmaxf(hp[idx], 0.f);
    out[idx] = x[idx] + (r - stats[o]) * stats[128 + o] + stats[256 + o];
  }
}

extern "C" void kernel_launch(void* const* d_in, const int* in_sizes, int n_in,
                              void* d_out, int out_size, void* d_ws, size_t ws_size,
                              hipStream_t stream) {
  const float* xyz1 = (const float*)d_in[0];
  const float* xyz2 = (const float*)d_in[1];
  const float* points1 = (const float*)d_in[2];
  const float* points2 = (const float*)d_in[3];
  const float* fuse_w = (const float*)d_in[4];
  const float* fuse_b = (const float*)d_in[5];
  const float* fuse_g = (const float*)d_in[6];
  const float* fuse_be = (const float*)d_in[7];
  const float* lu_w = (const float*)d_in[8];
  const float* lu_b = (const float*)d_in[9];
  const float* lu_g = (const float*)d_in[10];
  const float* lu_be = (const float*)d_in[11];
  (void)in_sizes; (void)n_in; (void)out_size; (void)ws_size;

  char* ws = (char*)d_ws;
  float* p2t = (float*)(ws);                   // 4,194,304 B  [B,S,C2]
  float* wW = (float*)(ws + 4194304);          //   196,608 B  [B,N,3]
  int* wIdx = (int*)(ws + 4390912);            //   196,608 B
  float* st1 = (float*)(ws + 4587520);         //     1,536 B
  float* st2 = (float*)(ws + 4589056);         //     1,536 B
  int* knn = (int*)(ws + 4590592);             // 1,048,576 B  [B,N,16]
  float* nt = (float*)(ws + 5639168);          // 25,165,824 B [B*N,384]
  float* xp = (float*)(ws + 30804992);         // 8,388,608 B  [B,CO,N]
  float* x = (float*)(ws + 39193600);          // 8,388,608 B  [B,CO,N]
  // nt is dead after the fuse GEMM -> reuse its 25.1 MB for xt/dxt/hp
  float* xt = nt;                  // [B,N,CO]
  float* dxt = nt + 2097152;       // [B*N,CO]
  float* hp = nt + 4194304;        // [B,CO,N]

  dim3 tb(32, 8);
  transpose_k<<<dim3(32, 8, NB), tb, 0, stream>>>(points2, p2t, 256, 1024, 262144L, 262144L, 256);
  transpose_k<<<dim3(128, 4, NB), tb, 0, stream>>>(points1, nt, 128, 4096, 524288L, 1572864L, 384);
  interp_top3_k<<<dim3(128, NB), 256, 0, stream>>>(xyz1, xyz2, wW, wIdx);
  interp_fill_k<<<8192, 256, 0, stream>>>(p2t, wW, wIdx, nt);
  gemm_bias_k<NCC><<<dim3(256, 2), 256, 0, stream>>>(nt, fuse_w, fuse_b, xp);
  bn_stats_k<<<128, 256, 0, stream>>>(xp, fuse_g, fuse_be, st1, 0);
  fuse_apply_k<<<dim3(128, 4, NB), tb, 0, stream>>>(xp, st1, x, xt);
  knn_k<<<dim3(128, NB), 256, 0, stream>>>(xyz1, knn);
  lap_gather_k<<<8192, 256, 0, stream>>>(xt, knn, dxt);
  gemm_bias_k<NCO><<<dim3(256, 2), 256, 0, stream>>>(dxt, lu_w, lu_b, hp);
  bn_stats_k<<<128, 256, 0, stream>>>(hp, lu_g, lu_be, st2, 1);
  final_k<<<2048, 256, 0, stream>>>(x, hp, st2, (float*)d_out);
}

// Round 19
// 258.551 us; speedup vs baseline: 1.6153x; 1.6153x over previous
//
#include <hip/hip_runtime.h>
#include <cfloat>

#define NB 4
#define NN 4096
#define NS 1024
#define NC1 128
#define NC2 256
#define NCO 128
#define NCC 384
#define NK 16
#define KCHUNK 2048
#define KCAP 160
#define KPAD 161

// NOTE on numerics: the reference computes squared distances in the EXPANDED
// form ||a||^2 + ||b||^2 - 2 a.b (see _sqdist). Top-k selections sit on
// near-ties whose resolution depends on the exact fp bits, so both selection
// kernels below replicate numpy's op order exactly with non-contractible
// __fmul_rn/__fadd_rn/__fsub_rn (no FMA fusion allowed).
//
// PERF CALIBRATION (measured R5-R18):
//  * LDS residency: 74,240 B/block -> 2 blocks/CU; 80,384 -> 1 block/CU.
//  * knn fallback (uncoalesced global rescan) ~100 us/trigger and stalls the
//    whole block -> tau MUST keep P(survivors > KCAP) ~ 0. Full-stream
//    per-lane top-2 tau (this version): ~37 mean survivors, P ~ 3.5e-7.
//    Chunk0-only tau (R16-R18): ~74 survivors -> deterministic fallback
//    storms -> 2.6x regression. Do not loosen tau.

__device__ __forceinline__ float norm3_np(float x, float y, float z) {
  return __fadd_rn(__fadd_rn(__fmul_rn(x, x), __fmul_rn(y, y)), __fmul_rn(z, z));
}

__device__ __forceinline__ float sqdist_np(float nq, float ns,
                                           float qx, float qy, float qz,
                                           float sx, float sy, float sz) {
  float dot = __fadd_rn(__fadd_rn(__fmul_rn(qx, sx), __fmul_rn(qy, sy)),
                        __fmul_rn(qz, sz));
  return __fsub_rn(__fadd_rn(nq, ns), __fmul_rn(2.0f, dot));
}

// ---------- generic 32x32 LDS-tiled transpose with strided output ----------
__global__ void transpose_k(const float* __restrict__ in, float* __restrict__ out,
                            int rows_in, int cols_in, long in_bs, long out_bs, int out_rs) {
  __shared__ float tile[32][33];
  const int b = blockIdx.z;
  const int c0 = blockIdx.x * 32, r0 = blockIdx.y * 32;
  const float* ib = in + (long)b * in_bs;
  float* ob = out + (long)b * out_bs;
#pragma unroll
  for (int k = 0; k < 32; k += 8) {
    tile[threadIdx.y + k][threadIdx.x] =
        ib[(long)(r0 + threadIdx.y + k) * cols_in + c0 + threadIdx.x];
  }
  __syncthreads();
#pragma unroll
  for (int k = 0; k < 32; k += 8) {
    ob[(long)(c0 + threadIdx.y + k) * out_rs + (r0 + threadIdx.x)] =
        tile[threadIdx.x][threadIdx.y + k];
  }
}

// ---------- 3-point interpolation: top-3 LARGEST distances (faithful) ----------
// block: 256 threads = 32 queries x 8 lanes; grid (N/32, B)
__global__ __launch_bounds__(256) void interp_top3_k(const float* __restrict__ xyz1,
                                                     const float* __restrict__ xyz2,
                                                     float* __restrict__ wW,
                                                     int* __restrict__ wIdx) {
  __shared__ float sx[NS], sy[NS], sz[NS], sn[NS];
  __shared__ float md[256 * 3];
  __shared__ int mi[256 * 3];
  const int b = blockIdx.y;
  const int tid = threadIdx.x;
  for (int i = tid; i < NS; i += 256) {
    long base = ((long)b * NS + i) * 3;
    float x = xyz2[base], y = xyz2[base + 1], z = xyz2[base + 2];
    sx[i] = x; sy[i] = y; sz[i] = z;
    sn[i] = norm3_np(x, y, z);
  }
  __syncthreads();
  const int q = (blockIdx.x << 5) + (tid >> 3);
  const int lane = tid & 7;
  long qb = ((long)b * NN + q) * 3;
  const float qx = xyz1[qb], qy = xyz1[qb + 1], qz = xyz1[qb + 2];
  const float nq = norm3_np(qx, qy, qz);
  float bd[3] = {-FLT_MAX, -FLT_MAX, -FLT_MAX};
  int bi[3] = {0x7fffffff, 0x7fffffff, 0x7fffffff};
  for (int s = lane; s < NS; s += 8) {
    float d = sqdist_np(nq, sn[s], qx, qy, qz, sx[s], sy[s], sz[s]);
    if (d > bd[2]) {   // guard: ladder is a no-op when d <= bd[2]
      float cd = d; int ci = s;
#pragma unroll
      for (int j = 0; j < 3; ++j) {
        bool gt = cd > bd[j];                // strict: tie keeps earlier (lower idx)
        float f = fmaxf(cd, bd[j]);
        float bk = fminf(cd, bd[j]);
        int fi = gt ? ci : bi[j];
        int ki = gt ? bi[j] : ci;
        bd[j] = f; bi[j] = fi; cd = bk; ci = ki;
      }
    }
  }
#pragma unroll
  for (int j = 0; j < 3; ++j) { md[tid * 3 + j] = bd[j]; mi[tid * 3 + j] = bi[j]; }
  __syncthreads();
  if (lane == 0) {
    int p0 = 0, p1 = 0, p2 = 0, p3 = 0, p4 = 0, p5 = 0, p6 = 0, p7 = 0;
    float od[3]; int oi[3];
#pragma unroll
    for (int j = 0; j < 3; ++j) {
      float bv = -FLT_MAX; int bidx = 0x7fffffff; int bl = 0;
#define ITOP_CAND(l, pl)                                                     \
      {                                                                      \
        float t = (pl < 3) ? md[(tid + l) * 3 + pl] : -FLT_MAX;              \
        int ti = (pl < 3) ? mi[(tid + l) * 3 + pl] : 0x7fffffff;             \
        if (t > bv || (t == bv && ti < bidx)) { bv = t; bidx = ti; bl = l; } \
      }
      ITOP_CAND(0, p0) ITOP_CAND(1, p1) ITOP_CAND(2, p2) ITOP_CAND(3, p3)
      ITOP_CAND(4, p4) ITOP_CAND(5, p5) ITOP_CAND(6, p6) ITOP_CAND(7, p7)
#undef ITOP_CAND
      od[j] = bv; oi[j] = bidx;
      p0 += (bl == 0); p1 += (bl == 1); p2 += (bl == 2); p3 += (bl == 3);
      p4 += (bl == 4); p5 += (bl == 5); p6 += (bl == 6); p7 += (bl == 7);
    }
    float r0 = 1.f / (od[0] + 1e-8f);
    float r1 = 1.f / (od[1] + 1e-8f);
    float r2 = 1.f / (od[2] + 1e-8f);
    float sR = __fadd_rn(__fadd_rn(r0, r1), r2);
    long obase = ((long)b * NN + q) * 3;
    wW[obase + 0] = r0 / sR; wW[obase + 1] = r1 / sR; wW[obase + 2] = r2 / sR;
    wIdx[obase + 0] = oi[0]; wIdx[obase + 1] = oi[1]; wIdx[obase + 2] = oi[2];
  }
}

// ---------- fill interp channels of nt (cols 128..383) ----------
__global__ __launch_bounds__(256) void interp_fill_k(const float* __restrict__ p2t,
                                                     const float* __restrict__ wW,
                                                     const int* __restrict__ wIdx,
                                                     float* __restrict__ nt) {
  const int q = (blockIdx.x << 1) + (threadIdx.x >> 7);
  const int co = threadIdx.x & 127;
  const int b = q >> 12;
  long wb = (long)q * 3;
  float w0 = wW[wb], w1 = wW[wb + 1], w2 = wW[wb + 2];
  int i0 = wIdx[wb], i1 = wIdx[wb + 1], i2 = wIdx[wb + 2];
  const float* r0 = p2t + ((long)(b << 10) + i0) * NC2;
  const float* r1 = p2t + ((long)(b << 10) + i1) * NC2;
  const float* r2 = p2t + ((long)(b << 10) + i2) * NC2;
  float* orow = nt + (long)q * NCC + NC1;
#pragma unroll
  for (int h = 0; h < 2; ++h) {
    int c = co + 128 * h;
    orow[c] = w0 * r0[c] + w1 * r1[c] + w2 * r2[c];
  }
}

// ---------- f32 tiled GEMM: 64 rows x 64 output channels per block ----------
// grid (M/64, CO/64) = (256, 2) -> 512 blocks = 2 blocks/CU = 2 waves/SIMD.
template <int C>
__global__ __launch_bounds__(256) void gemm_bias_k(const float* __restrict__ feat,
                                                   const float* __restrict__ W,
                                                   const float* __restrict__ bias,
                                                   float* __restrict__ out) {
  __shared__ float fL[64][36];
  __shared__ float wL[64][36];
  const int r0 = blockIdx.x * 64;
  const int ob = blockIdx.y * 64;
  const int tid = threadIdx.x;
  const int tn = tid & 15;
  const int to = tid >> 4;
  float acc[4][4];
#pragma unroll
  for (int i = 0; i < 4; ++i)
#pragma unroll
    for (int j = 0; j < 4; ++j) acc[i][j] = 0.f;

  for (int c0 = 0; c0 < C; c0 += 32) {
#pragma unroll
    for (int k = 0; k < 8; ++k) {
      int e = tid + 256 * k;
      int rr = e >> 5, cc = e & 31;
      fL[rr][cc] = feat[(long)(r0 + rr) * C + c0 + cc];
    }
#pragma unroll
    for (int k = 0; k < 8; ++k) {
      int e = tid + 256 * k;
      int rr = e >> 5, cc = e & 31;
      wL[rr][cc] = W[(long)(ob + rr) * C + c0 + cc];
    }
    __syncthreads();
#pragma unroll
    for (int cc4 = 0; cc4 < 32; cc4 += 4) {
      float4 fv[4], wv[4];
#pragma unroll
      for (int i = 0; i < 4; ++i) fv[i] = *(const float4*)&fL[tn + 16 * i][cc4];
#pragma unroll
      for (int j = 0; j < 4; ++j) wv[j] = *(const float4*)&wL[to + 16 * j][cc4];
#pragma unroll
      for (int i = 0; i < 4; ++i)
#pragma unroll
        for (int j = 0; j < 4; ++j) {
          acc[i][j] += fv[i].x * wv[j].x + fv[i].y * wv[j].y +
                       fv[i].z * wv[j].z + fv[i].w * wv[j].w;
        }
    }
    __syncthreads();
  }
  const int b = r0 >> 12;
  const int n0 = r0 & 4095;
#pragma unroll
  for (int i = 0; i < 4; ++i) {
    int n = n0 + tn + 16 * i;
#pragma unroll
    for (int j = 0; j < 4; ++j) {
      int o = ob + to + 16 * j;
      out[((long)(b * NCO + o) << 12) + n] = acc[i][j] + bias[o];
    }
  }
}

// ---------- BN stats per channel over (B, N): single pass (sum, sumsq) ----------
__global__ __launch_bounds__(256) void bn_stats_k(const float* __restrict__ v,
                                                  const float* __restrict__ gamma,
                                                  const float* __restrict__ beta,
                                                  float* __restrict__ stats, int relu_in) {
  __shared__ float rs[256], rq[256];
  const int o = blockIdx.x, tid = threadIdx.x;
  float s = 0.f, ss = 0.f;
  for (int i = tid; i < NB * NN; i += 256) {
    int b = i >> 12, n = i & 4095;
    float val = v[(((long)b * NCO + o) << 12) + n];
    if (relu_in) val = fmaxf(val, 0.f);
    s += val;
    ss += val * val;
  }
  rs[tid] = s; rq[tid] = ss;
  __syncthreads();
  for (int off = 128; off > 0; off >>= 1) {
    if (tid < off) { rs[tid] += rs[tid + off]; rq[tid] += rq[tid + off]; }
    __syncthreads();
  }
  if (tid == 0) {
    float m = rs[0] * (1.f / 16384.f);
    float var = rq[0] * (1.f / 16384.f) - m * m;
    var = fmaxf(var, 0.f);
    float inv = rsqrtf(var + 1e-5f);
    stats[o] = m;
    stats[128 + o] = inv * gamma[o];
    stats[256 + o] = beta[o];
  }
}

// ---------- apply fuse BN + ReLU (tiled): write x [B,CO,N] + xt [B,N,CO] ----------
// grid (N/32, CO/32, B), block (32,8).
__global__ void fuse_apply_k(const float* __restrict__ xp, const float* __restrict__ stats,
                             float* __restrict__ x, float* __restrict__ xt) {
  __shared__ float tile[32][33];
  const int b = blockIdx.z;
  const int n0 = blockIdx.x * 32;
  const int o0 = blockIdx.y * 32;
  const int tx = threadIdx.x, ty = threadIdx.y;
#pragma unroll
  for (int k = 0; k < 32; k += 8) {
    int o = o0 + ty + k;
    long idx = (((long)b * NCO + o) << 12) + n0 + tx;
    float v = (xp[idx] - stats[o]) * stats[128 + o] + stats[256 + o];
    v = fmaxf(v, 0.f);
    x[idx] = v;
    tile[ty + k][tx] = v;
  }
  __syncthreads();
#pragma unroll
  for (int k = 0; k < 32; k += 8) {
    int n = n0 + ty + k;
    xt[((long)(b << 12) + n) * NCO + o0 + tx] = tile[tx][ty + k];
  }
}

// ---------- KNN(16): tau + BALLOT compaction; 32 q x 8 lanes; 4-way ILP ----------
// (R15-proven version, reverted verbatim after R16-R18's single-restage
//  regressions.) Pass 1: FOUR independent top-2 trackers per lane over the
// FULL 4096-candidate stream (2 chunk stagings) -> union combine -> tau =
// max over query's 8 lanes of lane 2nd-smallest. >=16 candidates <= tau.
// Pass 2: 4 distances + 4 ballots per iteration; deterministic positions via
// popc prefix sums; register count, no atomics.
// Pass 3: order-independent lex-(d,idx) ladder + 8-way lex merge (proven).
// Overflow (mycnt > KCAP=160, P ~3.5e-7/query): tau-guarded global rescan.
__global__ __launch_bounds__(256) void knn_k(const float* __restrict__ xyz1,
                                             int* __restrict__ knn) {
  __shared__ float4 sc[KCHUNK];      // 32 KB; reused as merge lists at the end
  __shared__ float bufd[32][KPAD];   // 20.1 KB
  __shared__ int bufi[32][KPAD];     // 20.1 KB
  const int b = blockIdx.y;
  const int tid = threadIdx.x;
  const int ql = tid >> 3;
  const int q = (blockIdx.x << 5) + ql;
  const int lane = tid & 7;
  const int gb = (tid & 63) - lane;  // group base lane within the wave
  const long qb = ((long)b * NN + q) * 3;
  const float qx = xyz1[qb], qy = xyz1[qb + 1], qz = xyz1[qb + 2];
  const float nq = norm3_np(qx, qy, qz);

  // ---- pass 1: tau via FOUR independent top-2 trackers (full stream) ----
  float ta0 = FLT_MAX, ta1 = FLT_MAX, tb0 = FLT_MAX, tb1 = FLT_MAX;
  float tc0 = FLT_MAX, tc1 = FLT_MAX, td0 = FLT_MAX, td1 = FLT_MAX;
  for (int ch = 0; ch < 2; ++ch) {
    for (int i = tid; i < KCHUNK; i += 256) {
      long base = ((long)b * NN + ch * KCHUNK + i) * 3;
      float x = xyz1[base], y = xyz1[base + 1], z = xyz1[base + 2];
      sc[i] = make_float4(x, y, z, norm3_np(x, y, z));
    }
    __syncthreads();
    for (int i = lane; i < KCHUNK; i += 32) {
      float4 v0 = sc[i], v1 = sc[i + 8], v2 = sc[i + 16], v3 = sc[i + 24];
      float d0 = sqdist_np(nq, v0.w, qx, qy, qz, v0.x, v0.y, v0.z);
      float d1 = sqdist_np(nq, v1.w, qx, qy, qz, v1.x, v1.y, v1.z);
      float d2 = sqdist_np(nq, v2.w, qx, qy, qz, v2.x, v2.y, v2.z);
      float d3 = sqdist_np(nq, v3.w, qx, qy, qz, v3.x, v3.y, v3.z);
      float h0 = fmaxf(d0, ta0); ta0 = fminf(d0, ta0); ta1 = fminf(h0, ta1);
      float h1 = fmaxf(d1, tb0); tb0 = fminf(d1, tb0); tb1 = fminf(h1, tb1);
      float h2 = fmaxf(d2, tc0); tc0 = fminf(d2, tc0); tc1 = fminf(h2, tc1);
      float h3 = fmaxf(d3, td0); td0 = fminf(d3, td0); td1 = fminf(h3, td1);
    }
    __syncthreads();
  }
  // union combine: lane 2nd-smallest (exact ties -> looser tau: still safe)
  float m1 = fminf(fminf(ta0, tb0), fminf(tc0, td0));
  float s0 = (ta0 == m1) ? ta1 : ta0;
  float s1 = (tb0 == m1) ? tb1 : tb0;
  float s2 = (tc0 == m1) ? tc1 : tc0;
  float s3 = (td0 == m1) ? td1 : td0;
  float tau = fminf(fminf(s0, s1), fminf(s2, s3));
  tau = fmaxf(tau, __shfl_xor(tau, 1, 64));
  tau = fmaxf(tau, __shfl_xor(tau, 2, 64));
  tau = fmaxf(tau, __shfl_xor(tau, 4, 64));

  // ---- pass 2: ballot-compacted survivor collection (4-way ILP) ----
  int mycnt = 0;  // survivor count for this query; uniform across its 8 lanes
  for (int ch = 0; ch < 2; ++ch) {
    for (int i = tid; i < KCHUNK; i += 256) {
      long base = ((long)b * NN + ch * KCHUNK + i) * 3;
      float x = xyz1[base], y = xyz1[base + 1], z = xyz1[base + 2];
      sc[i] = make_float4(x, y, z, norm3_np(x, y, z));
    }
    __syncthreads();
    const int cb = ch * KCHUNK;
    for (int i = lane; i < KCHUNK; i += 32) {
      float4 v0 = sc[i], v1 = sc[i + 8], v2 = sc[i + 16], v3 = sc[i + 24];
      float d0 = sqdist_np(nq, v0.w, qx, qy, qz, v0.x, v0.y, v0.z);
      float d1 = sqdist_np(nq, v1.w, qx, qy, qz, v1.x, v1.y, v1.z);
      float d2 = sqdist_np(nq, v2.w, qx, qy, qz, v2.x, v2.y, v2.z);
      float d3 = sqdist_np(nq, v3.w, qx, qy, qz, v3.x, v3.y, v3.z);
      bool sv0 = (d0 <= tau), sv1 = (d1 <= tau), sv2 = (d2 <= tau), sv3 = (d3 <= tau);
      unsigned long long m0 = __ballot(sv0);
      unsigned long long m1b = __ballot(sv1);
      unsigned long long m2 = __ballot(sv2);
      unsigned long long m3 = __ballot(sv3);
      unsigned g0 = (unsigned)((m0 >> gb) & 0xFFull);
      unsigned g1 = (unsigned)((m1b >> gb) & 0xFFull);
      unsigned g2 = (unsigned)((m2 >> gb) & 0xFFull);
      unsigned g3 = (unsigned)((m3 >> gb) & 0xFFull);
      unsigned below = (1u << lane) - 1u;
      int c0p = __popc(g0), c1p = __popc(g1), c2p = __popc(g2);
      if (sv0) {
        int pos = mycnt + __popc(g0 & below);
        if (pos < KCAP) { bufd[ql][pos] = d0; bufi[ql][pos] = cb + i; }
      }
      if (sv1) {
        int pos = mycnt + c0p + __popc(g1 & below);
        if (pos < KCAP) { bufd[ql][pos] = d1; bufi[ql][pos] = cb + i + 8; }
      }
      if (sv2) {
        int pos = mycnt + c0p + c1p + __popc(g2 & below);
        if (pos < KCAP) { bufd[ql][pos] = d2; bufi[ql][pos] = cb + i + 16; }
      }
      if (sv3) {
        int pos = mycnt + c0p + c1p + c2p + __popc(g3 & below);
        if (pos < KCAP) { bufd[ql][pos] = d3; bufi[ql][pos] = cb + i + 24; }
      }
      mycnt += c0p + c1p + c2p + __popc(g3);
    }
    __syncthreads();
  }

  // ---- pass 3: exact stable top-16 ----
  float bd[NK]; int bi[NK];
#pragma unroll
  for (int j = 0; j < NK; ++j) { bd[j] = FLT_MAX; bi[j] = 0x7fffffff; }
  if (mycnt > KCAP) {
    // fallback: tau-guarded strict-d ladder over global (index order -> stable)
    for (int s = lane; s < NN; s += 8) {
      long base = ((long)b * NN + s) * 3;
      float x = xyz1[base], y = xyz1[base + 1], z = xyz1[base + 2];
      float d = sqdist_np(nq, norm3_np(x, y, z), qx, qy, qz, x, y, z);
      if (d <= tau) {
        float cd = d; int ci = s;
#pragma unroll
        for (int j = 0; j < NK; ++j) {
          bool lt = cd < bd[j];
          float dmin = fminf(cd, bd[j]);
          float dmax = fmaxf(cd, bd[j]);
          int imin = lt ? ci : bi[j];
          int imax = lt ? bi[j] : ci;
          bd[j] = dmin; bi[j] = imin; cd = dmax; ci = imax;
        }
      }
    }
  } else {
    for (int j0 = lane; j0 < mycnt; j0 += 8) {
      float cd = bufd[ql][j0]; int ci = bufi[ql][j0];
#pragma unroll
      for (int j = 0; j < NK; ++j) {
        bool lt = (cd < bd[j]) || (cd == bd[j] && ci < bi[j]);  // lex (d, idx)
        float nd = lt ? cd : bd[j];
        float xd = lt ? bd[j] : cd;
        int ni = lt ? ci : bi[j];
        int xi = lt ? bi[j] : ci;
        bd[j] = nd; bi[j] = ni; cd = xd; ci = xi;
      }
    }
  }
  __syncthreads();  // staging LDS dead; reuse sc for merge lists

  float* md = (float*)sc;        // 256*16 floats = 16 KB
  int* mi = (int*)sc + 4096;     // 256*16 ints  = 16 KB
#pragma unroll
  for (int j = 0; j < NK; ++j) { md[tid * NK + j] = bd[j]; mi[tid * NK + j] = bi[j]; }
  __syncthreads();
  if (lane == 0) {
    int p0 = 0, p1 = 0, p2 = 0, p3 = 0, p4 = 0, p5 = 0, p6 = 0, p7 = 0;
    long obase = ((long)b * NN + q) * NK;
    for (int j = 0; j < NK; ++j) {
      float bv = FLT_MAX; int bidx = 0x7fffffff; int bl = 0;
#define KNN_CAND(l, pl)                                                      \
      {                                                                      \
        float t = (pl < NK) ? md[(tid + l) * NK + pl] : FLT_MAX;             \
        int ti = (pl < NK) ? mi[(tid + l) * NK + pl] : 0x7fffffff;           \
        if (t < bv || (t == bv && ti < bidx)) { bv = t; bidx = ti; bl = l; } \
      }
      KNN_CAND(0, p0) KNN_CAND(1, p1) KNN_CAND(2, p2) KNN_CAND(3, p3)
      KNN_CAND(4, p4) KNN_CAND(5, p5) KNN_CAND(6, p6) KNN_CAND(7, p7)
#undef KNN_CAND
      knn[obase + j] = bidx;
      p0 += (bl == 0); p1 += (bl == 1); p2 += (bl == 2); p3 += (bl == 3);
      p4 += (bl == 4); p5 += (bl == 5); p6 += (bl == 6); p7 += (bl == 7);
    }
  }
}

// ---------- Laplacian gather: dxt[q][o] = sum_k xt[nbr_k][o] - xt[q][o] ----------
__global__ __launch_bounds__(256) void lap_gather_k(const float* __restrict__ xt,
                                                    const int* __restrict__ knn,
                                                    float* __restrict__ dxt) {
  const int q = (blockIdx.x << 1) + (threadIdx.x >> 7);
  const int o = threadIdx.x & 127;
  const int b = q >> 12;
  const int* kid = knn + (long)q * NK;
  const long bb = ((long)b << 12) * NCO;
  float s = 0.f;
#pragma unroll
  for (int k = 0; k < NK; ++k) {
    int m = kid[k];
    s += xt[bb + (long)m * NCO + o];
  }
  dxt[(long)q * NCO + o] = s - xt[(long)q * NCO + o];
}

// ---------- final: out = x + BN(relu(h_pre)) ----------
__global__ void final_k(const float* __restrict__ x, const float* __restrict__ hp,
                        const float* __restrict__ stats, float* __restrict__ out) {
  const int stride = gridDim.x * blockDim.x;
  for (int idx = blockIdx.x * blockDim.x + threadIdx.x; idx < NB * NCO * NN; idx += stride) {
    int o = (idx >> 12) & 127;
    float r = fmaxf(hp[idx], 0.f);
    out[idx] = x[idx] + (r - stats[o]) * stats[128 + o] + stats[256 + o];
  }
}

extern "C" void kernel_launch(void* const* d_in, const int* in_sizes, int n_in,
                              void* d_out, int out_size, void* d_ws, size_t ws_size,
                              hipStream_t stream) {
  const float* xyz1 = (const float*)d_in[0];
  const float* xyz2 = (const float*)d_in[1];
  const float* points1 = (const float*)d_in[2];
  const float* points2 = (const float*)d_in[3];
  const float* fuse_w = (const float*)d_in[4];
  const float* fuse_b = (const float*)d_in[5];
  const float* fuse_g = (const float*)d_in[6];
  const float* fuse_be = (const float*)d_in[7];
  const float* lu_w = (const float*)d_in[8];
  const float* lu_b = (const float*)d_in[9];
  const float* lu_g = (const float*)d_in[10];
  const float* lu_be = (const float*)d_in[11];
  (void)in_sizes; (void)n_in; (void)out_size; (void)ws_size;

  char* ws = (char*)d_ws;
  float* p2t = (float*)(ws);                   // 4,194,304 B  [B,S,C2]
  float* wW = (float*)(ws + 4194304);          //   196,608 B  [B,N,3]
  int* wIdx = (int*)(ws + 4390912);            //   196,608 B
  float* st1 = (float*)(ws + 4587520);         //     1,536 B
  float* st2 = (float*)(ws + 4589056);         //     1,536 B
  int* knn = (int*)(ws + 4590592);             // 1,048,576 B  [B,N,16]
  float* nt = (float*)(ws + 5639168);          // 25,165,824 B [B*N,384]
  float* xp = (float*)(ws + 30804992);         // 8,388,608 B  [B,CO,N]
  float* x = (float*)(ws + 39193600);          // 8,388,608 B  [B,CO,N]
  // nt is dead after the fuse GEMM -> reuse its 25.1 MB for xt/dxt/hp
  float* xt = nt;                  // [B,N,CO]
  float* dxt = nt + 2097152;       // [B*N,CO]
  float* hp = nt + 4194304;        // [B,CO,N]

  dim3 tb(32, 8);
  transpose_k<<<dim3(32, 8, NB), tb, 0, stream>>>(points2, p2t, 256, 1024, 262144L, 262144L, 256);
  transpose_k<<<dim3(128, 4, NB), tb, 0, stream>>>(points1, nt, 128, 4096, 524288L, 1572864L, 384);
  interp_top3_k<<<dim3(128, NB), 256, 0, stream>>>(xyz1, xyz2, wW, wIdx);
  interp_fill_k<<<8192, 256, 0, stream>>>(p2t, wW, wIdx, nt);
  gemm_bias_k<NCC><<<dim3(256, 2), 256, 0, stream>>>(nt, fuse_w, fuse_b, xp);
  bn_stats_k<<<128, 256, 0, stream>>>(xp, fuse_g, fuse_be, st1, 0);
  fuse_apply_k<<<dim3(128, 4, NB), tb, 0, stream>>>(xp, st1, x, xt);
  knn_k<<<dim3(128, NB), 256, 0, stream>>>(xyz1, knn);
  lap_gather_k<<<8192, 256, 0, stream>>>(xt, knn, dxt);
  gemm_bias_k<NCO><<<dim3(256, 2), 256, 0, stream>>>(dxt, lu_w, lu_b, hp);
  bn_stats_k<<<128, 256, 0, stream>>>(hp, lu_g, lu_be, st2, 1);
  final_k<<<2048, 256, 0, stream>>>(x, hp, st2, (float*)d_out);
}